// Round 18
// baseline (462.055 us; speedup 1.0000x reference)
//
#include <hip/hip_runtime.h>

#define Bc 32
#define Kc 64
#define Wc 100
#define Hc 150
#define H3c 450
#define KWc 6400
#define ALPHAc 0.2f
#define THRESc 0.0002f

typedef unsigned int u32;
typedef unsigned short u16;
typedef __attribute__((ext_vector_type(8))) short short8;   // 8 bf16
typedef __attribute__((ext_vector_type(4))) float floatx4;  // 4 f32 acc

// ---- ws layout (float offsets), 4.55 MB ----
#define OFF_WX      0u          // 204800  Wx (B,K,W) fp32
#define OFF_CS      204800u     // 2048    causesum (B,K)
#define OFF_GX      206848u     // 921600  gl proj (s,b,g)
#define OFF_HT      1128448u    // 4800    h_t (B,H)
#define OFF_Z       1133248u    // 4800    z (B,H)

__device__ __forceinline__ float us2f(u16 u){ u32 x=((u32)u)<<16; return __uint_as_float(x); }
__device__ __forceinline__ u16 f2us(float f){
  u32 x = __float_as_uint(f);
  u32 r = (x + 0x7fffu + ((x>>16)&1u)) >> 16;   // RNE bf16
  return (u16)r;
}

// LDS-only barrier: skips the vmcnt(0) drain __syncthreads would emit; global
// loads issued before it stay in flight (consumed via register deps).
__device__ __forceinline__ void lds_barrier(){
  __builtin_amdgcn_sched_barrier(0);
  asm volatile("s_waitcnt lgkmcnt(0)" ::: "memory");
  __builtin_amdgcn_s_barrier();
  __builtin_amdgcn_sched_barrier(0);
}

// ---------- Wx = x @ lin_w.T + lin_b ----------
__global__ void wx_kernel(const float* __restrict__ x, const float* __restrict__ lin_w,
                          const float* __restrict__ lin_b, float* __restrict__ ws){
  int o = blockIdx.x*256 + threadIdx.x;
  if (o >= Bc*KWc) return;
  int i = o % Wc;
  int bk = o / Wc;
  const float4* xr = (const float4*)(x + bk*Wc);
  const float4* wr = (const float4*)(lin_w + i*Wc);
  float acc = lin_b[i];
  #pragma unroll
  for (int j=0;j<25;j++){
    float4 xv = xr[j], wv = wr[j];
    acc += xv.x*wv.x + xv.y*wv.y + xv.z*wv.z + xv.w*wv.w;
  }
  ws[OFF_WX + o] = acc;
}

// ---------- attention softmax + thresholded sum (float4, __expf, log-threshold) ----------
__global__ void attn_kernel(const float* __restrict__ y, const float* __restrict__ a,
                            const float* __restrict__ bias, float* __restrict__ ws){
  __shared__ __align__(16) float e_l[KWc];
  __shared__ float red[4];
  int row = blockIdx.x;          // b*64 + k
  int b = row >> 6, k = row & 63;
  int tid = threadIdx.x;
  float a0 = a[0], a1 = a[1];
  float yv = y[row];
  const float4* v4  = (const float4*)(ws + OFF_WX + (size_t)b*KWc);
  const float4* br4 = (const float4*)(bias + (size_t)k*KWc);
  float4* e4 = (float4*)e_l;
  float ay = a0*yv;
  float m = -3.4e38f;
  for (int j=tid; j<KWc/4; j+=256){
    float4 vv = v4[j], bb = br4[j];
    float4 e;
    e.x = ay + a1*vv.x + bb.x; e.x = (e.x>=0.f)?e.x:ALPHAc*e.x;
    e.y = ay + a1*vv.y + bb.y; e.y = (e.y>=0.f)?e.y:ALPHAc*e.y;
    e.z = ay + a1*vv.z + bb.z; e.z = (e.z>=0.f)?e.z:ALPHAc*e.z;
    e.w = ay + a1*vv.w + bb.w; e.w = (e.w>=0.f)?e.w:ALPHAc*e.w;
    e4[j] = e;
    m = fmaxf(m, fmaxf(fmaxf(e.x,e.y), fmaxf(e.z,e.w)));
  }
  for (int o=32;o;o>>=1) m = fmaxf(m, __shfl_down(m, o));
  if ((tid&63)==0) red[tid>>6] = m;
  __syncthreads();
  m = fmaxf(fmaxf(red[0],red[1]), fmaxf(red[2],red[3]));
  __syncthreads();
  float ssum = 0.f;
  for (int j=tid; j<KWc/4; j+=256){
    float4 e = e4[j];
    ssum += __expf(e.x-m) + __expf(e.y-m) + __expf(e.z-m) + __expf(e.w-m);
  }
  for (int o=32;o;o>>=1) ssum += __shfl_down(ssum, o);
  if ((tid&63)==0) red[tid>>6] = ssum;
  __syncthreads();
  float s = red[0]+red[1]+red[2]+red[3];
  float thr = m + logf(THRESc * s);
  float cs = 0.f;
  for (int j=tid; j<KWc/4; j+=256){
    float4 e = e4[j];
    float4 vv = v4[j];
    if (e.x >= thr) cs += vv.x;
    if (e.y >= thr) cs += vv.y;
    if (e.z >= thr) cs += vv.z;
    if (e.w >= thr) cs += vv.w;
  }
  for (int o=32;o;o>>=1) cs += __shfl_down(cs, o);
  if ((tid&63)==0) red[tid>>6] = cs;
  __syncthreads();
  if (tid==0) ws[OFF_CS + row] = red[0]+red[1]+red[2]+red[3];
}

// ---------- gl input projection ----------
__global__ void glproj_kernel(const float* __restrict__ gl_wih, const float* __restrict__ gl_bih,
                              float* __restrict__ ws){
  int o = blockIdx.x*256 + threadIdx.x;
  if (o >= Kc*Bc*H3c) return;
  int g = o % H3c;
  int t = o / H3c;               // s*32 + b
  int b = t & 31, s = t >> 5;
  float cs = ws[OFF_CS + b*Kc + s];
  const float4* xr = (const float4*)(ws + OFF_WX + b*KWc + s*Wc);
  const float4* wr = (const float4*)(gl_wih + g*Wc);
  float acc = gl_bih[g];
  #pragma unroll
  for (int j=0;j<25;j++){
    float4 wv = wr[j], xv = xr[j];
    acc += (xv.x+cs)*wv.x + (xv.y+cs)*wv.y + (xv.z+cs)*wv.z + (xv.w+cs)*wv.w;
  }
  ws[OFF_GX + o] = acc;
}

// ---------- gl recurrent GRU v18: weights in LDS (allocator-proof) ----------
// 3 rounds of register-attribute fixes were no-ops; weights kept landing in scratch.
// Now bf16-pair weights live in LDS: wL[row][pair], row stride 78 u32 (312B, 8B-
// aligned -> ds_read_b64; gcd(78,32)=2 -> free 2-way bank alias). 145KB static LDS
// (143KB precedent ran in round 1). Reg demand ~25 -> scratch impossible.
__global__ void __attribute__((amdgpu_flat_work_group_size(1024,1024)))
glgru4_kernel(
    const float* __restrict__ gl_whh, const float* __restrict__ gl_bhh,
    const float* __restrict__ z_noise, const float* __restrict__ mu_w,
    const float* __restrict__ mu_b, const float* __restrict__ std_w,
    const float* __restrict__ std_b, float* __restrict__ ws){
  __shared__ __align__(16) u32 wL[450*78];        // 140,400 B
  __shared__ __align__(16) float hbuf[2][152];    // f32 h, rows 150/151 stay 0
  __shared__ __align__(16) float dotb[2][3][152]; // [half][gate][t]
  int b = blockIdx.x;            // one batch per block
  int tid = threadIdx.x;
  bool dotter = (tid < 900);
  int half = (tid >= 450) ? 1 : 0;
  int row  = dotter ? (tid - half*450) : 0;   // 0..449 = g*150+t
  int g = row/150, t = row - g*150;

  // stage weights: 450 rows x 76 pairs (pair 75 = zero pad for k=150,151)
  for (int item = tid; item < 450*76; item += 1024){
    int r = item / 76, j = item - r*76;
    u32 v = 0u;
    if (j < 75){
      float2 w2 = *(const float2*)(gl_whh + (size_t)r*Hc + 2*j);
      v = (u32)f2us(w2.x) | ((u32)f2us(w2.y) << 16);
    }
    wL[r*78 + j] = v;
  }
  if (tid < 152){ hbuf[0][tid] = 0.f; hbuf[1][tid] = 0.f; }

  float bh_r=0.f, bh_z=0.f, bh_n=0.f, hreg=0.f;
  if (tid < Hc){
    bh_r = gl_bhh[tid]; bh_z = gl_bhh[Hc+tid]; bh_n = gl_bhh[2*Hc+tid];
  }
  __syncthreads();   // wL + hbuf ready

  const u32* wrow = wL + row*78 + half*38;   // half0: pairs 0..37 (k0..75); half1: 38..75 (k76..151)
  for (int s=0;s<Kc;s++){
    int rb = s & 1;
    float gxr=0.f, gxz=0.f, gxn=0.f;
    if (tid < Hc){
      const float* gp = ws + OFF_GX + (size_t)(s*Bc + b)*H3c;
      gxr = gp[tid]; gxz = gp[Hc+tid]; gxn = gp[2*Hc+tid];
    }
    if (dotter){
      const float* hb = &hbuf[rb][half*76];
      float a0=0.f, a1=0.f;
      #pragma unroll
      for (int i=0;i<19;i++){
        u32 u0 = wrow[2*i], u1 = wrow[2*i+1];      // 8B-aligned -> ds_read_b64
        float4 h4 = *(const float4*)(hb + 4*i);    // broadcast
        a0 += __uint_as_float(u0<<16)        *h4.x;
        a1 += __uint_as_float(u0&0xffff0000u)*h4.y;
        a0 += __uint_as_float(u1<<16)        *h4.z;
        a1 += __uint_as_float(u1&0xffff0000u)*h4.w;
      }
      dotb[half][g][t] = a0 + a1;
    }
    lds_barrier();   // dots ready
    if (tid < Hc){
      float dr = dotb[0][0][tid] + dotb[1][0][tid];
      float dz = dotb[0][1][tid] + dotb[1][1][tid];
      float dn = dotb[0][2][tid] + dotb[1][2][tid];
      float a_r = gxr + dr + bh_r;
      float a_z = gxz + dz + bh_z;
      float rr = 1.f/(1.f+__expf(-a_r));
      float zz = 1.f/(1.f+__expf(-a_z));
      float nx = gxn + rr*(dn + bh_n);
      nx = fminf(fmaxf(nx,-15.f),15.f);
      float e2 = __expf(2.f*nx);
      float n = (e2-1.f)/(e2+1.f);
      float h = (1.f-zz)*n + zz*hreg;
      hreg = h;
      hbuf[rb^1][tid] = h;
    }
    lds_barrier();   // h ready; dotb consumed (WAR safe)
  }
  if (tid < Hc) ws[OFF_HT + (size_t)b*Hc + tid] = hreg;

  // ---- fused z = mu + exp(0.5*log_var)*noise ----
  if (tid < 300){
    int which = tid/150, tt = tid - which*150;
    const float* wrow2 = (which ? std_w : mu_w) + (size_t)tt*Hc;
    float acc = which ? std_b[tt] : mu_b[tt];
    const float* hb = hbuf[0];
    #pragma unroll
    for (int i=0;i<75;i++){
      float2 wv = *(const float2*)(wrow2 + 2*i);
      float2 hv = *(const float2*)(hb + 2*i);
      acc += wv.x*hv.x + wv.y*hv.y;
    }
    dotb[0][which][tt] = acc;
  }
  lds_barrier();
  if (tid < Hc){
    float mu = dotb[0][0][tid], lv = dotb[0][1][tid];
    float sg = expf(0.5f*lv);
    ws[OFF_Z + (size_t)b*Hc + tid] = mu + sg*z_noise[(size_t)b*Hc + tid];
  }
}

// ---------- causes v16 (frozen): v14 body + waves_per_eu(2,2) ----------
__global__ void __attribute__((amdgpu_flat_work_group_size(512,512), amdgpu_waves_per_eu(2,2)))
causes3_kernel(
    const float* __restrict__ net_wih, const float* __restrict__ net_whh,
    const float* __restrict__ net_bih, const float* __restrict__ net_bhh,
    const float* __restrict__ ws, float* __restrict__ out){
  __shared__ __align__(16) u16 bF[9*16*40];    // h: 5 chunks packed; x: 4 chunks
  __shared__ float g_rz[320*17];               // [row][16 lanes], stride 17
  __shared__ float g_nh[160*17];
  __shared__ float g_np[160*10];
  int kk = blockIdx.x & 63, bg = blockIdx.x >> 6, b0 = bg*8;
  int tid = threadIdx.x;
  int w = tid >> 6, lane = tid & 63, quad = lane >> 4, n16 = lane & 15;
  const float* whhk = net_whh + (size_t)kk*H3c*Hc;
  const float* wihk = net_wih + (size_t)kk*H3c*Wc;
  const float* bihk = net_bih + kk*H3c;
  const float* bhhk = net_bhh + kk*H3c;

  short8 whhA[4][5], wihA[4][4];
  #pragma unroll
  for (int ti=0; ti<4; ti++){
    int tile = w*4 + ti;
    int sec = tile/10;
    int sr = (tile - sec*10)*16 + n16;
    bool rowok = (tile < 30) && (sr < Hc);
    int grow = (sec<3 ? sec : 2)*Hc + sr;
    const float* wr = whhk + (size_t)grow*Hc;     // 600B stride: 8B-aligned
    #pragma unroll
    for (int c=0;c<5;c++){
      union { short8 v; u16 u[8]; } t8;
      #pragma unroll
      for (int j2=0;j2<4;j2++){
        int kk2 = c*32 + quad*8 + j2*2;
        float2 wv = (rowok && (kk2+1) < Hc) ? *(const float2*)(wr + kk2) : make_float2(0.f,0.f);
        t8.u[j2*2]   = f2us(wv.x);
        t8.u[j2*2+1] = f2us(wv.y);
      }
      whhA[ti][c] = t8.v;
    }
    const float* wr2 = wihk + (size_t)grow*Wc;    // 400B stride: 16B-aligned
    #pragma unroll
    for (int c=0;c<4;c++){
      union { short8 v; u16 u[8]; } t8;
      #pragma unroll
      for (int j4=0;j4<2;j4++){
        int kb = c*32 + quad*8 + j4*4;            // mult of 4 -> 16B-aligned
        float4 wv = (rowok && kb < Wc) ? *(const float4*)(wr2 + kb) : make_float4(0.f,0.f,0.f,0.f);
        t8.u[j4*4]   = f2us(wv.x);
        t8.u[j4*4+1] = f2us(wv.y);
        t8.u[j4*4+2] = f2us(wv.z);
        t8.u[j4*4+3] = f2us(wv.w);
      }
      wihA[ti][c] = t8.v;
    }
  }

  for (int i=tid; i<9*16*40/2; i+=512) ((u32*)bF)[i] = 0u;

  float hst[3] = {0.f,0.f,0.f};
  float brz_r[3], brz_z[3], bnh_[3], bnp_[3];
  #pragma unroll
  for (int q=0;q<3;q++){
    int task = tid + q*512;
    if (task < 1200){
      int t = task >> 3, bb = task & 7;
      float h = ws[OFF_Z + (b0+bb)*Hc + t];
      hst[q] = h;
      brz_r[q] = bhhk[t]      + bihk[t];
      brz_z[q] = bhhk[Hc+t]   + bihk[Hc+t];
      bnh_[q]  = bhhk[2*Hc+t];
      bnp_[q]  = bihk[2*Hc+t];
      u16 hi = f2us(h); float hif = us2f(hi); u16 lo = f2us(h - hif);
      bF[(t>>5)*640 + bb*40 + (t&31)] = hi;
      bF[(t>>5)*640 + (bb+8)*40 + (t&31)] = lo;
    }
  }
  for (int it=tid; it<800; it+=512){
    int bb = it/100, i = it - bb*100;
    float xv = ws[OFF_WX + (b0+bb)*KWc + i];
    bF[(5+(i>>5))*640 + bb*40 + (i&31)] = f2us(xv);
  }

  int bb0 = tid/100, i0 = tid - bb0*100;
  int it1 = tid + 512;
  int bb1 = it1/100, i1 = it1 - bb1*100;
  bool v1ok = (it1 < 800);

  const bool isN = (w >= 5);
  for (int s=0;s<Kc;s++){
    float xp0 = 0.f, xp1 = 0.f;
    if (s < Kc-1){
      xp0 = ws[OFF_WX + (size_t)(b0+bb0)*KWc + (s+1)*Wc + i0];
      if (v1ok) xp1 = ws[OFF_WX + (size_t)(b0+bb1)*KWc + (s+1)*Wc + i1];
    }
    lds_barrier();   // h+x staging ready
    const u16* bBase = bF + (size_t)n16*40 + (size_t)quad*8;
    short8 bx[4];
    #pragma unroll
    for (int c=0;c<4;c++) bx[c] = *(const short8*)(bBase + (size_t)(5+c)*640);
    short8 bh[5];
    #pragma unroll
    for (int c=0;c<5;c++) bh[c] = *(const short8*)(bBase + (size_t)c*640);
    // ---- phase A: wih . x ----
    floatx4 acc[4] = {{0.f,0.f,0.f,0.f},{0.f,0.f,0.f,0.f},{0.f,0.f,0.f,0.f},{0.f,0.f,0.f,0.f}};
    #pragma unroll
    for (int ca=0;ca<4;ca++){
      #pragma unroll
      for (int ti=0;ti<4;ti++)
        acc[ti] = __builtin_amdgcn_mfma_f32_16x16x32_bf16(wihA[ti][ca], bx[ca], acc[ti], 0,0,0);
    }
    if (isN){
      if (n16 < 8){
        #pragma unroll
        for (int ti=0;ti<4;ti++){
          int tile = w*4 + ti;
          if (tile < 30){
            int srb = (tile - 20)*16 + quad*4;
            float* gq = g_np + srb*10 + n16;
            #pragma unroll
            for (int r=0;r<4;r++) gq[r*10] = acc[ti][r];
          }
        }
      }
      #pragma unroll
      for (int ti=0;ti<4;ti++) acc[ti] = (floatx4){0.f,0.f,0.f,0.f};
    }
    // ---- phase B: whh . h, 5 packed chunks (hi cols 0-7, lo cols 8-15) ----
    #pragma unroll
    for (int c=0;c<5;c++){
      #pragma unroll
      for (int ti=0;ti<4;ti++)
        acc[ti] = __builtin_amdgcn_mfma_f32_16x16x32_bf16(whhA[ti][c], bh[c], acc[ti], 0,0,0);
    }
    // dual-dump: hi partial (lanes 0-7, includes wih.x) and lo partial (lanes 8-15)
    #pragma unroll
    for (int ti=0;ti<4;ti++){
      int tile = w*4 + ti;
      if (tile < 30){
        int sec = tile/10;
        int srb = (tile - sec*10)*16 + quad*4;
        if (sec < 2){
          float* gp = g_rz + (sec*160 + srb)*17 + n16;
          #pragma unroll
          for (int r=0;r<4;r++) gp[r*17] = acc[ti][r];
        } else {
          float* gh = g_nh + srb*17 + n16;
          #pragma unroll
          for (int r=0;r<4;r++) gh[r*17] = acc[ti][r];
        }
      }
    }
    lds_barrier();   // gates ready; bF MFMA reads done
    #pragma unroll
    for (int q=0;q<3;q++){
      int task = tid + q*512;
      if (task < 1200){
        int t = task >> 3, bb = task & 7;
        float a_r = g_rz[t*17+bb] + g_rz[t*17+bb+8] + brz_r[q];
        float a_z = g_rz[(160+t)*17+bb] + g_rz[(160+t)*17+bb+8] + brz_z[q];
        float nhv = g_nh[t*17+bb] + g_nh[t*17+bb+8];
        float r  = 1.f/(1.f+__expf(-a_r));
        float zz = 1.f/(1.f+__expf(-a_z));
        float nx = (g_np[t*10+bb] + bnp_[q]) + r*(nhv + bnh_[q]);
        nx = fminf(fmaxf(nx,-15.f),15.f);
        float e2 = __expf(2.f*nx);
        float n = (e2-1.f)/(e2+1.f);
        float h = (1.f-zz)*n + zz*hst[q];
        hst[q] = h;
        u16 hi = f2us(h); float hif = us2f(hi); u16 lo = f2us(h - hif);
        bF[(t>>5)*640 + bb*40 + (t&31)] = hi;
        bF[(t>>5)*640 + (bb+8)*40 + (t&31)] = lo;
      }
    }
    if (s < Kc-1){
      bF[(5+(i0>>5))*640 + bb0*40 + (i0&31)] = f2us(xp0);
      if (v1ok) bF[(5+(i1>>5))*640 + bb1*40 + (i1&31)] = f2us(xp1);
    }
  }
  #pragma unroll
  for (int q=0;q<3;q++){
    int task = tid + q*512;
    if (task < 1200){
      int t = task >> 3, bb = task & 7;
      out[((size_t)(b0+bb)*Kc + kk)*Hc + t] = hst[q];
    }
  }
}

extern "C" void kernel_launch(void* const* d_in, const int* in_sizes, int n_in,
                              void* d_out, int out_size, void* d_ws, size_t ws_size,
                              hipStream_t stream){
  const float* x        = (const float*)d_in[0];
  const float* y        = (const float*)d_in[1];
  const float* z_noise  = (const float*)d_in[2];
  const float* lin_w    = (const float*)d_in[3];
  const float* lin_b    = (const float*)d_in[4];
  const float* a        = (const float*)d_in[5];
  const float* bias     = (const float*)d_in[6];
  const float* gl_wih   = (const float*)d_in[7];
  const float* gl_whh   = (const float*)d_in[8];
  const float* gl_bih   = (const float*)d_in[9];
  const float* gl_bhh   = (const float*)d_in[10];
  const float* mu_w     = (const float*)d_in[11];
  const float* mu_b     = (const float*)d_in[12];
  const float* std_w    = (const float*)d_in[13];
  const float* std_b    = (const float*)d_in[14];
  const float* net_wih  = (const float*)d_in[15];
  const float* net_whh  = (const float*)d_in[16];
  const float* net_bih  = (const float*)d_in[17];
  const float* net_bhh  = (const float*)d_in[18];
  float* ws = (float*)d_ws;
  float* out = (float*)d_out;

  wx_kernel<<<(Bc*KWc+255)/256, 256, 0, stream>>>(x, lin_w, lin_b, ws);
  attn_kernel<<<Bc*Kc, 256, 0, stream>>>(y, a, bias, ws);
  glproj_kernel<<<(Kc*Bc*H3c+255)/256, 256, 0, stream>>>(gl_wih, gl_bih, ws);
  glgru4_kernel<<<Bc, 1024, 0, stream>>>(gl_whh, gl_bhh, z_noise, mu_w, mu_b, std_w, std_b, ws);
  causes3_kernel<<<Kc*4, 512, 0, stream>>>(net_wih, net_whh, net_bih, net_bhh, ws, out);
}